// Round 2
// baseline (616.078 us; speedup 1.0000x reference)
//
#include <hip/hip_runtime.h>
#include <hip/hip_bf16.h>

// Problem: B=64, C=512, H=W=28, NL=4. All tensors fp32. Per layer:
//   seq = mean_HW(x); (ht,ct)=cell(seq,ht,ct); out_h=cell(seq, ht[0], ct[0]).h
//   x = x*(1+out_h) + depthwise3x3(x)
// cell: g = W2·relu(W1·in) + Wh2·relu(Wh1·hx) + biases; i,f,c = split(g,3)
//       ncx = sig(f)*cx + sig(i)*tanh(c); h = sig(ncx)
// cell2's g_i path == cell1's g_i path (same input seq, same weights) -> reuse G_i.

#define HW 784
#define NPLANES 32768   // B*C
#define CC 512
#define BB 64

__device__ __forceinline__ float sigm(float x) { return 1.f / (1.f + __expf(-x)); }

// ---- zero init for ht/ct ----
__global__ void zero_kernel(float* p, int n) {
    int i = blockIdx.x * blockDim.x + threadIdx.x;
    if (i < n) p[i] = 0.f;
}

// ---- mean over HW per (b,c) plane; one wave per plane ----
__global__ void pool_kernel(const float* __restrict__ x, float* __restrict__ seq) {
    int wave = threadIdx.x >> 6, lane = threadIdx.x & 63;
    int p = blockIdx.x * 4 + wave;
    if (p >= NPLANES) return;
    const float4* b4 = (const float4*)(x + (size_t)p * HW);  // 196 float4 groups
    float s = 0.f;
    for (int j = lane; j < 196; j += 64) {
        float4 v = b4[j];
        s += v.x + v.y + v.z + v.w;
    }
    for (int off = 32; off > 0; off >>= 1) s += __shfl_down(s, off, 64);
    if (lane == 0) seq[p] = s * (1.f / 784.f);
}

// ---- hid_i = relu(seq·W_ih1^T + b), hid_h = relu(ht·W_hh1^T + b) : [64,32] each ----
__global__ void cell_a_kernel(const float* __restrict__ seq, const float* __restrict__ ht,
                              const float* __restrict__ w_ih1, const float* __restrict__ b_ih1,
                              const float* __restrict__ w_hh1, const float* __restrict__ b_hh1,
                              float* __restrict__ hid_i, float* __restrict__ hid_h) {
    __shared__ float s_in[2][CC];
    int b = blockIdx.x, t = threadIdx.x;  // 64 threads
    for (int k = t; k < CC; k += 64) {
        s_in[0][k] = seq[b * CC + k];
        s_in[1][k] = ht[b * CC + k];
    }
    __syncthreads();
    int which = t >> 5, j = t & 31;
    const float* w = which ? w_hh1 : w_ih1;
    const float* bias = which ? b_hh1 : b_ih1;
    const float* in = s_in[which];
    float acc = bias[j];
    for (int k = 0; k < CC; k++) acc += in[k] * w[j * CC + k];
    acc = fmaxf(acc, 0.f);
    (which ? hid_h : hid_i)[b * 32 + j] = acc;
}

// ---- G_i[b,1536], gates, ht/ct update (cell 1) ----
__global__ void cell_b_kernel(const float* __restrict__ hid_i, const float* __restrict__ hid_h,
                              const float* __restrict__ w_ih2, const float* __restrict__ b_ih2,
                              const float* __restrict__ w_hh2, const float* __restrict__ b_hh2,
                              float* __restrict__ G_i, float* __restrict__ ht, float* __restrict__ ct) {
    __shared__ float s_hi[32], s_hh[32], s_g[1536];
    int b = blockIdx.x, t = threadIdx.x;  // 256 threads
    if (t < 32) s_hi[t] = hid_i[b * 32 + t];
    else if (t < 64) s_hh[t - 32] = hid_h[b * 32 + (t - 32)];
    __syncthreads();
    for (int o = t; o < 1536; o += 256) {
        float gi = b_ih2[o], gh = b_hh2[o];
        const float* wi = w_ih2 + o * 32;
        const float* wh = w_hh2 + o * 32;
        for (int k = 0; k < 32; k++) {
            gi += s_hi[k] * wi[k];
            gh += s_hh[k] * wh[k];
        }
        G_i[b * 1536 + o] = gi;
        s_g[o] = gi + gh;
    }
    __syncthreads();
    for (int c = t; c < CC; c += 256) {
        float ig = s_g[c], fg = s_g[CC + c], cg = s_g[2 * CC + c];
        float nc = sigm(fg) * ct[b * CC + c] + sigm(ig) * tanhf(cg);
        ct[b * CC + c] = nc;
        ht[b * CC + c] = sigm(nc);
    }
}

// ---- g_h2[1536] from updated ht[0] (cell 2 hidden path) ----
__global__ void cell_c_kernel(const float* __restrict__ ht,
                              const float* __restrict__ w_hh1, const float* __restrict__ b_hh1,
                              const float* __restrict__ w_hh2, const float* __restrict__ b_hh2,
                              float* __restrict__ g_h2) {
    __shared__ float s_h0[CC];
    __shared__ float s_hid[32];
    int t = threadIdx.x;  // 256 threads
    for (int k = t; k < CC; k += 256) s_h0[k] = ht[k];
    __syncthreads();
    if (t < 32) {
        float acc = b_hh1[t];
        for (int k = 0; k < CC; k++) acc += s_h0[k] * w_hh1[t * CC + k];
        s_hid[t] = fmaxf(acc, 0.f);
    }
    __syncthreads();
    for (int o = t; o < 1536; o += 256) {
        float acc = b_hh2[o];
        const float* wh = w_hh2 + o * 32;
        for (int k = 0; k < 32; k++) acc += s_hid[k] * wh[k];
        g_h2[o] = acc;
    }
}

// ---- y = x*(1+out_h) + dwconv3x3(x); one block per (b,c) plane; in-place safe ----
__global__ void update_kernel(const float* __restrict__ x, float* __restrict__ y,
                              const float* __restrict__ G_i, const float* __restrict__ g_h2,
                              const float* __restrict__ ct, const float* __restrict__ dwk) {
    __shared__ float tile[30 * 30];
    __shared__ float s_w[9];
    __shared__ float s_oh;
    int p = blockIdx.x;
    int b = p >> 9, c = p & 511;
    int t = threadIdx.x;  // 256 threads
    const float* xp = x + (size_t)p * HW;
    for (int i = t; i < 900; i += 256) {
        int ty = i / 30, tx = i - ty * 30;
        int sy = ty - 1, sx = tx - 1;
        float v = 0.f;
        if ((unsigned)sy < 28u && (unsigned)sx < 28u) v = xp[sy * 28 + sx];
        tile[i] = v;
    }
    if (t < 9) s_w[t] = dwk[c * 9 + t];
    if (t == 0) {
        const float* g = G_i + b * 1536;
        float ig = g[c] + g_h2[c];
        float fg = g[CC + c] + g_h2[CC + c];
        float cg = g[2 * CC + c] + g_h2[2 * CC + c];
        float nc = sigm(fg) * ct[c] + sigm(ig) * tanhf(cg);  // ct[0] row broadcast
        s_oh = sigm(nc);
    }
    __syncthreads();
    float oh = s_oh;
    float w0 = s_w[0], w1 = s_w[1], w2 = s_w[2], w3 = s_w[3], w4 = s_w[4];
    float w5 = s_w[5], w6 = s_w[6], w7 = s_w[7], w8 = s_w[8];
    float* yp = y + (size_t)p * HW;
    for (int i = t; i < HW; i += 256) {
        int py = i / 28, px = i - py * 28;
        const float* tc = &tile[py * 30 + px];  // top-left of 3x3 window
        float re = tc[0] * w0 + tc[1] * w1 + tc[2] * w2
                 + tc[30] * w3 + tc[31] * w4 + tc[32] * w5
                 + tc[60] * w6 + tc[61] * w7 + tc[62] * w8;
        float cen = tc[31];
        yp[i] = cen * (1.f + oh) + re;
    }
}

extern "C" void kernel_launch(void* const* d_in, const int* in_sizes, int n_in,
                              void* d_out, int out_size, void* d_ws, size_t ws_size,
                              hipStream_t stream) {
    const float* x_in  = (const float*)d_in[0];
    const float* w_ih1 = (const float*)d_in[1];
    const float* b_ih1 = (const float*)d_in[2];
    const float* w_ih2 = (const float*)d_in[3];
    const float* b_ih2 = (const float*)d_in[4];
    const float* w_hh1 = (const float*)d_in[5];
    const float* b_hh1 = (const float*)d_in[6];
    const float* w_hh2 = (const float*)d_in[7];
    const float* b_hh2 = (const float*)d_in[8];
    const float* dwk   = (const float*)d_in[9];
    float* out = (float*)d_out;
    char* ws = (char*)d_ws;

    float* seq   = (float*)(ws + 0);        // 64*512 f32   = 131072 B
    float* hid_i = (float*)(ws + 131072);   // 64*32        = 8192 B
    float* hid_h = (float*)(ws + 139264);   // 64*32        = 8192 B
    float* G_i   = (float*)(ws + 147456);   // 64*1536      = 393216 B
    float* ht    = (float*)(ws + 540672);   // 64*512       = 131072 B
    float* ct    = (float*)(ws + 671744);   // 64*512       = 131072 B
    float* g_h2  = (float*)(ws + 802816);   // 1536         = 6144 B

    // zero ht, ct (ws is re-poisoned before every launch)
    zero_kernel<<<(2 * BB * CC + 255) / 256, 256, 0, stream>>>(ht, 2 * BB * CC);

    for (int layer = 0; layer < 4; layer++) {
        const float* xcur = (layer == 0) ? x_in : out;

        // phase A: pooled means
        pool_kernel<<<NPLANES / 4, 256, 0, stream>>>(xcur, seq);

        // cell computations (tiny)
        cell_a_kernel<<<BB, 64, 0, stream>>>(seq, ht, w_ih1, b_ih1, w_hh1, b_hh1, hid_i, hid_h);
        cell_b_kernel<<<BB, 256, 0, stream>>>(hid_i, hid_h, w_ih2, b_ih2, w_hh2, b_hh2, G_i, ht, ct);
        cell_c_kernel<<<1, 256, 0, stream>>>(ht, w_hh1, b_hh1, w_hh2, b_hh2, g_h2);

        // phase B: depthwise conv + gated update (in-place safe: LDS staging + barrier)
        update_kernel<<<NPLANES, 256, 0, stream>>>(xcur, out, G_i, g_h2, ct, dwk);
    }
}

// Round 3
// 460.193 us; speedup vs baseline: 1.3387x; 1.3387x over previous
//
#include <hip/hip_runtime.h>
#include <hip/hip_bf16.h>

// B=64, C=512, H=W=28, NL=4. All fp32. Per layer:
//   seq = mean_HW(x); (ht,ct)=cell(seq,ht,ct); out_h=cell(seq, ht[0], ct[0]).h
//   x = x*(1+out_h) + depthwise3x3(x)
// Fusions: pool folded into previous update's epilogue (layers 1-3);
//          all cell matvecs in one kernel (block 0 appends the g_h2 tail).

#define HW 784
#define F4 196        // float4 per plane
#define NPLANES 32768 // B*C
#define CC 512
#define BB 64
#define TS 31         // LDS tile row stride (30x30 tile, +1 pad)

__device__ __forceinline__ float sigm(float x) { return 1.f / (1.f + __expf(-x)); }

__global__ void zero_kernel(float* p, int n) {
    int i = blockIdx.x * blockDim.x + threadIdx.x;
    if (i < n) p[i] = 0.f;
}

// ---- mean over HW per plane (layer 0 only); one wave per plane ----
__global__ void pool_kernel(const float* __restrict__ x, float* __restrict__ seq) {
    int wave = threadIdx.x >> 6, lane = threadIdx.x & 63;
    int p = blockIdx.x * 4 + wave;
    const float4* b4 = (const float4*)(x + (size_t)p * HW);
    float s = 0.f;
    for (int j = lane; j < F4; j += 64) {
        float4 v = b4[j];
        s += v.x + v.y + v.z + v.w;
    }
    for (int off = 32; off > 0; off >>= 1) s += __shfl_down(s, off, 64);
    if (lane == 0) seq[p] = s * (1.f / 784.f);
}

// ---- all cell math for one layer: hid -> G_i, ht, ct; block 0 also g_h2 ----
__global__ void __launch_bounds__(256) cell_fused_kernel(
        const float* __restrict__ seq,
        const float* __restrict__ w_ih1, const float* __restrict__ b_ih1,
        const float* __restrict__ w_ih2, const float* __restrict__ b_ih2,
        const float* __restrict__ w_hh1, const float* __restrict__ b_hh1,
        const float* __restrict__ w_hh2, const float* __restrict__ b_hh2,
        float* __restrict__ G_i, float* __restrict__ ht, float* __restrict__ ct,
        float* __restrict__ g_h2) {
    __shared__ float s_in[2][CC];   // seq row, ht row
    __shared__ float s_hid[64];     // hid_i[0:32], hid_h[32:64]
    __shared__ float s_g[1536];
    __shared__ float s_h0[CC];      // block 0: new ht row 0
    __shared__ float s_hid2[32];
    int b = blockIdx.x, t = threadIdx.x;  // 256 threads

    for (int k = t; k < CC; k += 256) {
        s_in[0][k] = seq[b * CC + k];
        s_in[1][k] = ht[b * CC + k];
    }
    __syncthreads();

    // stage A: hid_{i,h}[j] = relu(b + <in, W1[j,:]>); 64 outputs x 4 lanes
    {
        int o = t >> 2, q = t & 3;          // o: 0..63, groups of 4 consecutive lanes
        int which = o >> 5, j = o & 31;
        const float* w = (which ? w_hh1 : w_ih1) + j * CC + q * 128;
        const float* in = s_in[which] + q * 128;
        float acc = 0.f;
        #pragma unroll 8
        for (int k = 0; k < 128; k++) acc += in[k] * w[k];
        acc += __shfl_down(acc, 2, 64);
        acc += __shfl_down(acc, 1, 64);
        if (q == 0) s_hid[o] = fmaxf(acc + (which ? b_hh1 : b_ih1)[j], 0.f);
    }
    __syncthreads();

    // stage B: G_i[b,o] and g = G_i + G_h
    for (int o = t; o < 1536; o += 256) {
        float gi = b_ih2[o], gh = b_hh2[o];
        const float* wi = w_ih2 + o * 32;
        const float* wh = w_hh2 + o * 32;
        #pragma unroll
        for (int k = 0; k < 32; k++) {
            gi += s_hid[k] * wi[k];
            gh += s_hid[32 + k] * wh[k];
        }
        G_i[b * 1536 + o] = gi;
        s_g[o] = gi + gh;
    }
    __syncthreads();

    // stage C: gates -> ct, ht
    for (int c = t; c < CC; c += 256) {
        float nc = sigm(s_g[CC + c]) * ct[b * CC + c] + sigm(s_g[c]) * tanhf(s_g[2 * CC + c]);
        ct[b * CC + c] = nc;
        float h = sigm(nc);
        ht[b * CC + c] = h;
        s_h0[c] = h;
    }
    if (b != 0) return;  // uniform per block; only block 0 runs the cell-2 hidden path
    __syncthreads();

    // stage D: hid2 = relu(W_hh1 . ht0 + b_hh1); 32 outputs x 8 lanes
    {
        int o = t >> 3, q = t & 7;
        const float* w = w_hh1 + o * CC + q * 64;
        const float* in = s_h0 + q * 64;
        float acc = 0.f;
        #pragma unroll 8
        for (int k = 0; k < 64; k++) acc += in[k] * w[k];
        acc += __shfl_down(acc, 4, 64);
        acc += __shfl_down(acc, 2, 64);
        acc += __shfl_down(acc, 1, 64);
        if (q == 0) s_hid2[o] = fmaxf(acc + b_hh1[o], 0.f);
    }
    __syncthreads();

    // stage E: g_h2 = W_hh2 . hid2 + b_hh2
    for (int o = t; o < 1536; o += 256) {
        float acc = b_hh2[o];
        const float* wh = w_hh2 + o * 32;
        #pragma unroll
        for (int k = 0; k < 32; k++) acc += s_hid2[k] * wh[k];
        g_h2[o] = acc;
    }
}

// ---- y = x*(1+oh) + dw3x3(x); fused mean(y) -> seq_next. One block per plane ----
__global__ void __launch_bounds__(256) update_kernel(
        const float* __restrict__ x, float* __restrict__ y,
        const float* __restrict__ G_i, const float* __restrict__ g_h2,
        const float* __restrict__ ct0, const float* __restrict__ dwk,
        float* __restrict__ seq_next) {
    __shared__ float tile[30 * TS];
    __shared__ float s_w[9];
    __shared__ float s_oh;
    __shared__ float s_part[256];
    int p = blockIdx.x;
    int b = p >> 9, c = p & 511;
    int t = threadIdx.x;  // 256 threads, 196 own one float4 each

    // zero the halo border (rows 0/29 cols 0..29; cols 0/29 rows 1..28)
    if (t < 30) tile[t] = 0.f;
    else if (t < 60) tile[29 * TS + (t - 30)] = 0.f;
    else if (t < 88) tile[(t - 59) * TS] = 0.f;
    else if (t < 116) tile[(t - 87) * TS + 29] = 0.f;
    if (t < 9) s_w[t] = dwk[c * 9 + t];
    if (t == 255) {
        const float* g = G_i + b * 1536;
        float ig = g[c] + g_h2[c];
        float fg = g[CC + c] + g_h2[CC + c];
        float cg = g[2 * CC + c] + g_h2[2 * CC + c];
        float nc = sigm(fg) * ct0[c] + sigm(ig) * tanhf(cg);
        s_oh = sigm(nc);
    }

    int py = t / 7, px4 = t - py * 7;  // t<196: output row, float4 col
    if (t < F4) {
        float4 v = ((const float4*)(x + (size_t)p * HW))[t];
        float* dst = &tile[(py + 1) * TS + px4 * 4 + 1];
        dst[0] = v.x; dst[1] = v.y; dst[2] = v.z; dst[3] = v.w;
    }
    __syncthreads();

    float sum = 0.f;
    if (t < F4) {
        float oh1 = 1.f + s_oh;
        float w0 = s_w[0], w1 = s_w[1], w2 = s_w[2], w3 = s_w[3], w4 = s_w[4];
        float w5 = s_w[5], w6 = s_w[6], w7 = s_w[7], w8 = s_w[8];
        const float* r0 = &tile[py * TS + px4 * 4];
        const float* r1 = r0 + TS;
        const float* r2 = r0 + 2 * TS;
        float a0 = r0[0], a1 = r0[1], a2 = r0[2], a3 = r0[3], a4 = r0[4], a5 = r0[5];
        float b0 = r1[0], b1 = r1[1], b2 = r1[2], b3 = r1[3], b4 = r1[4], b5 = r1[5];
        float c0 = r2[0], c1 = r2[1], c2 = r2[2], c3 = r2[3], c4 = r2[4], c5 = r2[5];
        float y0 = b1 * oh1 + a0 * w0 + a1 * w1 + a2 * w2 + b0 * w3 + b1 * w4 + b2 * w5 + c0 * w6 + c1 * w7 + c2 * w8;
        float y1 = b2 * oh1 + a1 * w0 + a2 * w1 + a3 * w2 + b1 * w3 + b2 * w4 + b3 * w5 + c1 * w6 + c2 * w7 + c3 * w8;
        float y2 = b3 * oh1 + a2 * w0 + a3 * w1 + a4 * w2 + b2 * w3 + b3 * w4 + b4 * w5 + c2 * w6 + c3 * w7 + c4 * w8;
        float y3 = b4 * oh1 + a3 * w0 + a4 * w1 + a5 * w2 + b3 * w3 + b4 * w4 + b5 * w5 + c3 * w6 + c4 * w7 + c5 * w8;
        ((float4*)(y + (size_t)p * HW))[t] = make_float4(y0, y1, y2, y3);
        sum = y0 + y1 + y2 + y3;
    }
    s_part[t] = sum;
    __syncthreads();
    if (t < 64) {
        float s = s_part[t] + s_part[t + 64] + s_part[t + 128] + s_part[t + 192];
        for (int off = 32; off > 0; off >>= 1) s += __shfl_down(s, off, 64);
        if (t == 0) seq_next[p] = s * (1.f / 784.f);
    }
}

extern "C" void kernel_launch(void* const* d_in, const int* in_sizes, int n_in,
                              void* d_out, int out_size, void* d_ws, size_t ws_size,
                              hipStream_t stream) {
    const float* x_in  = (const float*)d_in[0];
    const float* w_ih1 = (const float*)d_in[1];
    const float* b_ih1 = (const float*)d_in[2];
    const float* w_ih2 = (const float*)d_in[3];
    const float* b_ih2 = (const float*)d_in[4];
    const float* w_hh1 = (const float*)d_in[5];
    const float* b_hh1 = (const float*)d_in[6];
    const float* w_hh2 = (const float*)d_in[7];
    const float* b_hh2 = (const float*)d_in[8];
    const float* dwk   = (const float*)d_in[9];
    float* out = (float*)d_out;
    char* ws = (char*)d_ws;

    float* seq  = (float*)(ws + 0);        // 64*512  = 131072 B
    float* G_i  = (float*)(ws + 131072);   // 64*1536 = 393216 B
    float* ht   = (float*)(ws + 524288);   // 64*512  = 131072 B
    float* ct   = (float*)(ws + 655360);   // 64*512  = 131072 B (contiguous after ht)
    float* g_h2 = (float*)(ws + 786432);   // 1536    = 6144 B

    zero_kernel<<<(2 * BB * CC + 255) / 256, 256, 0, stream>>>(ht, 2 * BB * CC);
    pool_kernel<<<NPLANES / 4, 256, 0, stream>>>(x_in, seq);

    for (int layer = 0; layer < 4; layer++) {
        const float* xcur = (layer == 0) ? x_in : out;
        cell_fused_kernel<<<BB, 256, 0, stream>>>(seq, w_ih1, b_ih1, w_ih2, b_ih2,
                                                  w_hh1, b_hh1, w_hh2, b_hh2,
                                                  G_i, ht, ct, g_h2);
        // update also produces seq for the next layer's cell
        update_kernel<<<NPLANES, 256, 0, stream>>>(xcur, out, G_i, g_h2, ct, dwk, seq);
    }
}